// Round 5
// baseline (293.421 us; speedup 1.0000x reference)
//
#include <hip/hip_runtime.h>

typedef _Float16 f16;
typedef _Float16 f16x8 __attribute__((ext_vector_type(8)));
typedef _Float16 f16x4v __attribute__((ext_vector_type(4)));
typedef float f32x4 __attribute__((ext_vector_type(4)));

#define DEVINL __device__ __forceinline__

DEVINL void gload16(const void* g, void* l) {
  __builtin_amdgcn_global_load_lds(
      (const __attribute__((address_space(1))) void*)g,
      (__attribute__((address_space(3))) void*)l, 16, 0, 0);
}

// ---------------------------------------------------------------------------
// weff3 (unchanged): WT[n][k] = (W[k][n] + la[k][:]·lb[:][n]) * scale
// ---------------------------------------------------------------------------
__global__ __launch_bounds__(256) void weff3(
    const float* __restrict__ W, const float* __restrict__ la,
    const float* __restrict__ lb, f16* __restrict__ WT,
    int N, int K, int scaleCols)
{
  __shared__ float La[64][36];
  __shared__ f16 Ts[64][72];
  int t = threadIdx.x;
  int n0 = blockIdx.x * 64, k0 = blockIdx.y * 64;
  int w = t >> 6, nn = t & 63;
  #pragma unroll
  for (int i = 0; i < 8; ++i) {
    int idx = i * 256 + t;
    int row = idx >> 5, r = idx & 31;
    La[row][r] = la[(size_t)(k0 + row) * 32 + r];
  }
  float lbr[32];
  #pragma unroll
  for (int r = 0; r < 32; ++r) lbr[r] = lb[(size_t)r * N + n0 + nn];
  float scale = (n0 + nn < scaleCols) ? 0.125f : 1.0f;
  __syncthreads();
  float prev = 0.0f;
  #pragma unroll
  for (int i = 0; i < 16; ++i) {
    int k = w * 16 + i;
    float acc = W[(size_t)(k0 + k) * N + n0 + nn];
    #pragma unroll
    for (int rc = 0; rc < 8; ++rc) {
      float4 a4 = *(const float4*)&La[k][rc * 4];
      acc += a4.x * lbr[rc * 4] + a4.y * lbr[rc * 4 + 1] +
             a4.z * lbr[rc * 4 + 2] + a4.w * lbr[rc * 4 + 3];
    }
    acc *= scale;
    if (i & 1) {
      union { f16 h[2]; unsigned u; } pk;
      pk.h[0] = (f16)prev; pk.h[1] = (f16)acc;
      *(unsigned*)&Ts[nn][k - 1] = pk.u;
    } else prev = acc;
  }
  __syncthreads();
  #pragma unroll
  for (int it = 0; it < 2; ++it) {
    int id = it * 256 + t;
    int row = id >> 3, c8 = id & 7;
    f16x8 h = *(const f16x8*)&Ts[row][c8 * 8];
    *(f16x8*)(WT + (size_t)(n0 + row) * K + k0 + c8 * 8) = h;
  }
}

// ---------------------------------------------------------------------------
__global__ __launch_bounds__(256) void cvt_f32_f16(const float* __restrict__ in,
                                                   f16* __restrict__ out)
{
  int i = (blockIdx.x * 256 + threadIdx.x) * 4;
  float4 v = *(const float4*)(in + i);
  f16x4v o = {(f16)v.x, (f16)v.y, (f16)v.z, (f16)v.w};
  *(f16x4v*)(out + i) = o;
}

// ---------------------------------------------------------------------------
__global__ __launch_bounds__(256) void mask_canon(const unsigned char* __restrict__ m,
                                                  unsigned char* __restrict__ out)
{
  __shared__ int flag;
  if (threadIdx.x == 0) flag = 0;
  __syncthreads();
  int found = 0;
  for (int p = threadIdx.x; p < 12288; p += 256)
    if ((p & 3) && m[p]) found = 1;
  if (found) flag = 1;
  __syncthreads();
  int u8 = flag;
  const int* mi = (const int*)m;
  for (int idx = threadIdx.x; idx < 4096; idx += 256) {
    int b = idx >> 9, k = idx & 511;
    int v = u8 ? (int)m[b * 1536 + k] : mi[b * 1536 + k];
    out[idx] = (unsigned char)(v != 0);
  }
}

// ---------------------------------------------------------------------------
// 128x128 GEMM, BK=32, 4 waves (2x2 of 64x64), mfma_f32_16x16x32_f16.
// COUNTED-VMCNT PIPELINE: 3 LDS buffers, prefetch distance 2. Per K-tile,
// each wave issues 4 global_load_lds for tile t+2, then waits vmcnt(8)
// (= tiles t+1,t+2 still in flight, tile t provably landed), raw s_barrier.
// Loads stay in flight across 2 full K-iterations — no per-step queue drain.
// Swizzle: 64B rows, content LDS[r][c]=G[r][c^((r>>1)&3)] via pre-swizzled
// source; read XOR (lr>>1)&3 (HW-verified conflict-free, R4 counters).
// XCD remap: contiguous bm-stripe per XCD (A L2-resident, B streams).
// ---------------------------------------------------------------------------
template <int EPI>
__global__ __launch_bounds__(256, 3) void gemmk(
    const f16* __restrict__ A, const f16* __restrict__ Bt,
    int M, int N, int K,
    const float* __restrict__ bias, const f16* __restrict__ resid,
    f16* __restrict__ outH, float* __restrict__ outF,
    f16* __restrict__ Qo, f16* __restrict__ Ko, f16* __restrict__ Vto)
{
  __shared__ __align__(16) f16 As[3][128 * 32];
  __shared__ __align__(16) f16 Bs[3][128 * 32];
  int tid = threadIdx.x, wid = tid >> 6, l = tid & 63;
  int lg = l >> 4, lr = l & 15;
  int nbx = gridDim.x;
  int flat = blockIdx.y * nbx + blockIdx.x;
  int xcd = flat & 7, idx = flat >> 3;
  int mc = nbx >> 3;
  int bm = (xcd * mc + idx % mc) * 128;
  int bn = (idx / mc) * 128;
  int wr = (wid >> 1) * 64, wc = (wid & 1) * 64;
  f32x4 acc[4][4] = {};

  int swz = ((l & 3) ^ ((l >> 3) & 3)) * 8;   // source chunk involution
  const f16* gA = A + (size_t)(bm + wid * 32 + (l >> 2)) * K + swz;
  const f16* gB = Bt + (size_t)(bn + wid * 32 + (l >> 2)) * K + swz;
  int lofs = wid * 32 * 32;                   // wave's 32-row slice
  int xr = (lr >> 1) & 3;                     // read-side XOR

  f16* A0 = As[0]; f16* A1 = As[1]; f16* A2 = As[2];
  f16* B0 = Bs[0]; f16* B1 = Bs[1]; f16* B2 = Bs[2];

  // prologue: stage tiles 0 and 1 (4 gloads each per wave)
  #pragma unroll
  for (int ig = 0; ig < 2; ++ig) {
    gload16(gA + (size_t)(ig * 16) * K, A0 + lofs + ig * 16 * 32);
    gload16(gB + (size_t)(ig * 16) * K, B0 + lofs + ig * 16 * 32);
  }
  #pragma unroll
  for (int ig = 0; ig < 2; ++ig) {
    gload16(gA + (size_t)(ig * 16) * K + 32, A1 + lofs + ig * 16 * 32);
    gload16(gB + (size_t)(ig * 16) * K + 32, B1 + lofs + ig * 16 * 32);
  }

  int nt = K >> 5;
  for (int t = 0; t < nt; ++t) {
    if (t + 2 < nt) {
      int k2 = (t + 2) << 5;
      #pragma unroll
      for (int ig = 0; ig < 2; ++ig) {
        gload16(gA + (size_t)(ig * 16) * K + k2, A2 + lofs + ig * 16 * 32);
        gload16(gB + (size_t)(ig * 16) * K + k2, B2 + lofs + ig * 16 * 32);
      }
      asm volatile("s_waitcnt vmcnt(8)" ::: "memory");   // tile t landed
    } else if (t + 2 == nt) {
      asm volatile("s_waitcnt vmcnt(4)" ::: "memory");
    } else {
      asm volatile("s_waitcnt vmcnt(0)" ::: "memory");
    }
    __builtin_amdgcn_s_barrier();                        // tile t ready for all

    f16x8 af[4], bf[4];
    #pragma unroll
    for (int i = 0; i < 4; ++i)
      af[i] = *(const f16x8*)(A0 + (wr + i * 16 + lr) * 32 + ((lg ^ xr) * 8));
    #pragma unroll
    for (int j = 0; j < 4; ++j)
      bf[j] = *(const f16x8*)(B0 + (wc + j * 16 + lr) * 32 + ((lg ^ xr) * 8));
    __builtin_amdgcn_s_setprio(1);
    #pragma unroll
    for (int i = 0; i < 4; ++i)
      #pragma unroll
      for (int j = 0; j < 4; ++j)
        acc[i][j] = __builtin_amdgcn_mfma_f32_16x16x32_f16(af[i], bf[j], acc[i][j], 0, 0, 0);
    __builtin_amdgcn_s_setprio(0);
    __builtin_amdgcn_sched_barrier(0);
    __builtin_amdgcn_s_barrier();   // all reads of buf0 done -> reusable

    f16* tA = A0; A0 = A1; A1 = A2; A2 = tA;   // rotate cur<-next<-free
    f16* tB = B0; B0 = B1; B1 = B2; B2 = tB;
  }

  #pragma unroll
  for (int i = 0; i < 4; ++i) {
    #pragma unroll
    for (int j = 0; j < 4; ++j) {
      int n = bn + wc + j * 16 + lr;
      float bv = (EPI >= 1) ? bias[n] : 0.0f;
      #pragma unroll
      for (int r = 0; r < 4; ++r) {
        int m = bm + wr + i * 16 + lg * 4 + r;
        float v = acc[i][j][r];
        if (EPI == 0) {
          int bb = m >> 9, ss = m & 511;
          int which = n >> 10, c = n & 1023, hh = c >> 6, dd = c & 63;
          size_t base = (size_t)(bb * 16 + hh);
          if (which == 0)      Qo[(base * 512 + ss) * 64 + dd] = (f16)v;
          else if (which == 1) Ko[(base * 512 + ss) * 64 + dd] = (f16)v;
          else                 Vto[(base * 64 + dd) * 512 + ss] = (f16)v;
        } else if (EPI == 1) {
          v += bv;
          v = 0.5f * v * (1.0f + erff(v * 0.70710678118654752f));
          outH[(size_t)m * N + n] = (f16)v;
        } else if (EPI == 2) {
          v += bv + (float)resid[(size_t)m * N + n];
          outH[(size_t)m * N + n] = (f16)v;
        } else {
          outF[(size_t)m * N + n] = v + bv;
        }
      }
    }
  }
}

// ---------------------------------------------------------------------------
// Flash attention (unchanged from R4): 4 waves x 32 q-rows, T14 reg-staging,
// swizzled LDS, XCD remap.
// ---------------------------------------------------------------------------
__global__ __launch_bounds__(256, 2) void attn_kernel(
    const f16* __restrict__ Q, const f16* __restrict__ Kc,
    const f16* __restrict__ Vt, const unsigned char* __restrict__ cmask,
    f16* __restrict__ XO)
{
  __shared__ __align__(16) f16 Ks[128 * 64];
  __shared__ __align__(16) f16 Vs[64 * 128];
  __shared__ __align__(16) f16 Ps[4 * 32 * 128];
  int tid = threadIdx.x, w = tid >> 6, l = tid & 63;
  int lg = l >> 4, lr = l & 15;
  int flat = blockIdx.y * 4 + blockIdx.x;
  flat = (flat & 7) * 64 + (flat >> 3);
  int qblk = flat & 3, bh = flat >> 2;
  int b = bh >> 4, h = bh & 15;
  const f16* Qg = Q + (size_t)bh * 512 * 64 + qblk * 128 * 64;
  const f16* Kg = Kc + (size_t)bh * 512 * 64;
  const f16* Vg = Vt + (size_t)bh * 64 * 512;
  const unsigned char* mb = cmask + b * 512;

  f16x8 qf[2][2];
  #pragma unroll
  for (int i = 0; i < 2; ++i)
    #pragma unroll
    for (int kc = 0; kc < 2; ++kc)
      qf[i][kc] = *(const f16x8*)(Qg + (size_t)(w * 32 + i * 16 + lr) * 64 + kc * 32 + lg * 8);

  f32x4 O[2][4] = {};
  float mrow[2][4], lrow[2][4];
  #pragma unroll
  for (int i = 0; i < 2; ++i)
    #pragma unroll
    for (int r = 0; r < 4; ++r) { mrow[i][r] = -1e30f; lrow[i][r] = 0.0f; }

  f16* Pw = Ps + w * 32 * 128;

  int kR = tid >> 3, kC = (tid & 7) * 8;
  int vR = tid >> 4, vC = (tid & 15) * 8;
  f16x8 kreg[4], vreg[4];
  #pragma unroll
  for (int i = 0; i < 4; ++i) {
    kreg[i] = *(const f16x8*)(Kg + (size_t)(i * 32 + kR) * 64 + kC);
    vreg[i] = *(const f16x8*)(Vg + (size_t)(i * 16 + vR) * 512 + vC);
  }

  for (int kt = 0; kt < 4; ++kt) {
    #pragma unroll
    for (int i = 0; i < 4; ++i) {
      int krow = i * 32 + kR;
      *(f16x8*)(Ks + krow * 64 + (((tid & 7) ^ (krow & 7)) * 8)) = kreg[i];
      int vrow = i * 16 + vR;
      *(f16x8*)(Vs + vrow * 128 + (((tid & 15) ^ (vrow & 7)) * 8)) = vreg[i];
    }
    __syncthreads();
    if (kt < 3) {
      #pragma unroll
      for (int i = 0; i < 4; ++i) {
        kreg[i] = *(const f16x8*)(Kg + (size_t)((kt + 1) * 128 + i * 32 + kR) * 64 + kC);
        vreg[i] = *(const f16x8*)(Vg + (size_t)(i * 16 + vR) * 512 + (kt + 1) * 128 + vC);
      }
    }

    int x = lr & 7;
    f32x4 sc[2][8] = {};
    __builtin_amdgcn_s_setprio(1);
    #pragma unroll
    for (int j = 0; j < 8; ++j) {
      const f16* krow = Ks + (j * 16 + lr) * 64;
      f16x8 kf0 = *(const f16x8*)(krow + ((lg ^ x) * 8));
      f16x8 kf1 = *(const f16x8*)(krow + (((4 + lg) ^ x) * 8));
      sc[0][j] = __builtin_amdgcn_mfma_f32_16x16x32_f16(qf[0][0], kf0, sc[0][j], 0, 0, 0);
      sc[0][j] = __builtin_amdgcn_mfma_f32_16x16x32_f16(qf[0][1], kf1, sc[0][j], 0, 0, 0);
      sc[1][j] = __builtin_amdgcn_mfma_f32_16x16x32_f16(qf[1][0], kf0, sc[1][j], 0, 0, 0);
      sc[1][j] = __builtin_amdgcn_mfma_f32_16x16x32_f16(qf[1][1], kf1, sc[1][j], 0, 0, 0);
    }
    __builtin_amdgcn_s_setprio(0);
    bool keep[8];
    #pragma unroll
    for (int j = 0; j < 8; ++j) keep[j] = mb[kt * 128 + j * 16 + lr] != 0;
    #pragma unroll
    for (int i = 0; i < 2; ++i)
      #pragma unroll
      for (int j = 0; j < 8; ++j)
        #pragma unroll
        for (int r = 0; r < 4; ++r)
          sc[i][j][r] = keep[j] ? sc[i][j][r] : -1e30f;

    #pragma unroll
    for (int i = 0; i < 2; ++i) {
      #pragma unroll
      for (int r = 0; r < 4; ++r) {
        float pm = sc[i][0][r];
        #pragma unroll
        for (int j = 1; j < 8; ++j) pm = fmaxf(pm, sc[i][j][r]);
        pm = fmaxf(pm, __shfl_xor(pm, 1));
        pm = fmaxf(pm, __shfl_xor(pm, 2));
        pm = fmaxf(pm, __shfl_xor(pm, 4));
        pm = fmaxf(pm, __shfl_xor(pm, 8));
        float mn = fmaxf(mrow[i][r], pm);
        float alpha = __expf(mrow[i][r] - mn);
        mrow[i][r] = mn;
        lrow[i][r] *= alpha;
        #pragma unroll
        for (int jd = 0; jd < 4; ++jd) O[i][jd][r] *= alpha;
      }
    }
    #pragma unroll
    for (int i = 0; i < 2; ++i) {
      float rs[4] = {0.f, 0.f, 0.f, 0.f};
      #pragma unroll
      for (int j = 0; j < 8; ++j)
        #pragma unroll
        for (int r = 0; r < 4; ++r) {
          float p = __expf(sc[i][j][r] - mrow[i][r]);
          rs[r] += p;
          int prow = i * 16 + lg * 4 + r;
          int pc = j * 16 + lr;
          Pw[prow * 128 + ((((pc >> 3) ^ (prow & 7)) << 3) | (pc & 7))] = (f16)p;
        }
      #pragma unroll
      for (int r = 0; r < 4; ++r) {
        float s = rs[r];
        s += __shfl_xor(s, 1); s += __shfl_xor(s, 2);
        s += __shfl_xor(s, 4); s += __shfl_xor(s, 8);
        lrow[i][r] += s;
      }
    }
    __builtin_amdgcn_s_setprio(1);
    #pragma unroll
    for (int kk = 0; kk < 4; ++kk) {
      int c0 = ((kk * 4 + lg) ^ x) * 8;
      f16x8 pa0 = *(const f16x8*)(Pw + lr * 128 + c0);
      f16x8 pa1 = *(const f16x8*)(Pw + (16 + lr) * 128 + c0);
      #pragma unroll
      for (int jd = 0; jd < 4; ++jd) {
        f16x8 vb = *(const f16x8*)(Vs + (jd * 16 + lr) * 128 + c0);
        O[0][jd] = __builtin_amdgcn_mfma_f32_16x16x32_f16(pa0, vb, O[0][jd], 0, 0, 0);
        O[1][jd] = __builtin_amdgcn_mfma_f32_16x16x32_f16(pa1, vb, O[1][jd], 0, 0, 0);
      }
    }
    __builtin_amdgcn_s_setprio(0);
    __syncthreads();
  }

  #pragma unroll
  for (int i = 0; i < 2; ++i)
    #pragma unroll
    for (int r = 0; r < 4; ++r) {
      int q = qblk * 128 + w * 32 + i * 16 + lg * 4 + r;
      float inv = 1.0f / lrow[i][r];
      #pragma unroll
      for (int jd = 0; jd < 4; ++jd) {
        int c = h * 64 + jd * 16 + lr;
        XO[((size_t)b * 512 + q) * 1024 + c] = (f16)(O[i][jd][r] * inv);
      }
    }
}

// ---------------------------------------------------------------------------
extern "C" void kernel_launch(void* const* d_in, const int* in_sizes, int n_in,
                              void* d_out, int out_size, void* d_ws, size_t ws_size,
                              hipStream_t stream)
{
  (void)in_sizes; (void)n_in; (void)out_size; (void)ws_size;
  const float* x            = (const float*)d_in[0];
  const unsigned char* mask = (const unsigned char*)d_in[1];
  const float* qkv_w   = (const float*)d_in[2];
  const float* qkv_la  = (const float*)d_in[3];
  const float* qkv_lb  = (const float*)d_in[4];
  const float* proj_w  = (const float*)d_in[5];
  const float* proj_b  = (const float*)d_in[6];
  const float* proj_la = (const float*)d_in[7];
  const float* proj_lb = (const float*)d_in[8];
  const float* fc1_w   = (const float*)d_in[9];
  const float* fc1_b   = (const float*)d_in[10];
  const float* fc1_la  = (const float*)d_in[11];
  const float* fc1_lb  = (const float*)d_in[12];
  const float* fc2_w   = (const float*)d_in[13];
  const float* fc2_b   = (const float*)d_in[14];
  const float* fc2_la  = (const float*)d_in[15];
  const float* fc2_lb  = (const float*)d_in[16];
  float* out = (float*)d_out;

  f16* p = (f16*)d_ws;
  f16* WqkvT = p; p += 3072 * 1024;
  f16* W1T   = p; p += 1024 * 1024;
  f16* W2T   = p; p += 1024 * 1024;
  f16* WpT   = p; p += 1024 * 1024;
  f16* Xh    = p; p += 4096 * 1024;
  f16* Qb    = p; p += 128 * 512 * 64;
  f16* Kb    = p; p += 128 * 512 * 64;
  f16* Vt    = p; p += 128 * 64 * 512;
  f16* XO    = p; p += 4096 * 1024;
  unsigned char* cmask = (unsigned char*)p;
  f16* Hb  = Qb;
  f16* XO2 = Xh;

  weff3<<<dim3(48, 16), 256, 0, stream>>>(qkv_w, qkv_la, qkv_lb, WqkvT, 3072, 1024, 1024);
  weff3<<<dim3(16, 16), 256, 0, stream>>>(fc1_w, fc1_la, fc1_lb, W1T, 1024, 1024, 0);
  weff3<<<dim3(16, 16), 256, 0, stream>>>(fc2_w, fc2_la, fc2_lb, W2T, 1024, 1024, 0);
  weff3<<<dim3(16, 16), 256, 0, stream>>>(proj_w, proj_la, proj_lb, WpT, 1024, 1024, 0);
  cvt_f32_f16<<<4096, 256, 0, stream>>>(x, Xh);
  mask_canon<<<1, 256, 0, stream>>>(mask, cmask);

  gemmk<0><<<dim3(32, 24), 256, 0, stream>>>(Xh, WqkvT, 4096, 3072, 1024,
      nullptr, nullptr, nullptr, nullptr, Qb, Kb, Vt);
  attn_kernel<<<dim3(4, 128), 256, 0, stream>>>(Qb, Kb, Vt, cmask, XO);
  gemmk<1><<<dim3(32, 8), 256, 0, stream>>>(XO, W1T, 4096, 1024, 1024,
      fc1_b, nullptr, Hb, nullptr, nullptr, nullptr, nullptr);
  gemmk<2><<<dim3(32, 8), 256, 0, stream>>>(Hb, W2T, 4096, 1024, 1024,
      fc2_b, XO, XO2, nullptr, nullptr, nullptr, nullptr);
  gemmk<3><<<dim3(32, 8), 256, 0, stream>>>(XO2, WpT, 4096, 1024, 1024,
      proj_b, nullptr, nullptr, out, nullptr, nullptr, nullptr);
}

// Round 6
// 283.084 us; speedup vs baseline: 1.0365x; 1.0365x over previous
//
#include <hip/hip_runtime.h>

typedef _Float16 f16;
typedef _Float16 f16x8 __attribute__((ext_vector_type(8)));
typedef _Float16 f16x4v __attribute__((ext_vector_type(4)));
typedef float f32x4 __attribute__((ext_vector_type(4)));

#define DEVINL __device__ __forceinline__

DEVINL void gload16(const void* g, void* l) {
  __builtin_amdgcn_global_load_lds(
      (const __attribute__((address_space(1))) void*)g,
      (__attribute__((address_space(3))) void*)l, 16, 0, 0);
}

// ---------------------------------------------------------------------------
// weff3 (unchanged): WT[n][k] = (W[k][n] + la[k][:]·lb[:][n]) * scale
// ---------------------------------------------------------------------------
__global__ __launch_bounds__(256) void weff3(
    const float* __restrict__ W, const float* __restrict__ la,
    const float* __restrict__ lb, f16* __restrict__ WT,
    int N, int K, int scaleCols)
{
  __shared__ float La[64][36];
  __shared__ f16 Ts[64][72];
  int t = threadIdx.x;
  int n0 = blockIdx.x * 64, k0 = blockIdx.y * 64;
  int w = t >> 6, nn = t & 63;
  #pragma unroll
  for (int i = 0; i < 8; ++i) {
    int idx = i * 256 + t;
    int row = idx >> 5, r = idx & 31;
    La[row][r] = la[(size_t)(k0 + row) * 32 + r];
  }
  float lbr[32];
  #pragma unroll
  for (int r = 0; r < 32; ++r) lbr[r] = lb[(size_t)r * N + n0 + nn];
  float scale = (n0 + nn < scaleCols) ? 0.125f : 1.0f;
  __syncthreads();
  float prev = 0.0f;
  #pragma unroll
  for (int i = 0; i < 16; ++i) {
    int k = w * 16 + i;
    float acc = W[(size_t)(k0 + k) * N + n0 + nn];
    #pragma unroll
    for (int rc = 0; rc < 8; ++rc) {
      float4 a4 = *(const float4*)&La[k][rc * 4];
      acc += a4.x * lbr[rc * 4] + a4.y * lbr[rc * 4 + 1] +
             a4.z * lbr[rc * 4 + 2] + a4.w * lbr[rc * 4 + 3];
    }
    acc *= scale;
    if (i & 1) {
      union { f16 h[2]; unsigned u; } pk;
      pk.h[0] = (f16)prev; pk.h[1] = (f16)acc;
      *(unsigned*)&Ts[nn][k - 1] = pk.u;
    } else prev = acc;
  }
  __syncthreads();
  #pragma unroll
  for (int it = 0; it < 2; ++it) {
    int id = it * 256 + t;
    int row = id >> 3, c8 = id & 7;
    f16x8 h = *(const f16x8*)&Ts[row][c8 * 8];
    *(f16x8*)(WT + (size_t)(n0 + row) * K + k0 + c8 * 8) = h;
  }
}

// ---------------------------------------------------------------------------
__global__ __launch_bounds__(256) void cvt_f32_f16(const float* __restrict__ in,
                                                   f16* __restrict__ out)
{
  int i = (blockIdx.x * 256 + threadIdx.x) * 4;
  float4 v = *(const float4*)(in + i);
  f16x4v o = {(f16)v.x, (f16)v.y, (f16)v.z, (f16)v.w};
  *(f16x4v*)(out + i) = o;
}

// ---------------------------------------------------------------------------
__global__ __launch_bounds__(256) void mask_canon(const unsigned char* __restrict__ m,
                                                  unsigned char* __restrict__ out)
{
  __shared__ int flag;
  if (threadIdx.x == 0) flag = 0;
  __syncthreads();
  int found = 0;
  for (int p = threadIdx.x; p < 12288; p += 256)
    if ((p & 3) && m[p]) found = 1;
  if (found) flag = 1;
  __syncthreads();
  int u8 = flag;
  const int* mi = (const int*)m;
  for (int idx = threadIdx.x; idx < 4096; idx += 256) {
    int b = idx >> 9, k = idx & 511;
    int v = u8 ? (int)m[b * 1536 + k] : mi[b * 1536 + k];
    out[idx] = (unsigned char)(v != 0);
  }
}

// ---------------------------------------------------------------------------
// gemm0 (FROZEN from R5): 128x128, BK=32, 3-buffer counted vmcnt(8).
// ---------------------------------------------------------------------------
template <int EPI>
__global__ __launch_bounds__(256, 3) void gemmk(
    const f16* __restrict__ A, const f16* __restrict__ Bt,
    int M, int N, int K,
    const float* __restrict__ bias, const f16* __restrict__ resid,
    f16* __restrict__ outH, float* __restrict__ outF,
    f16* __restrict__ Qo, f16* __restrict__ Ko, f16* __restrict__ Vto)
{
  __shared__ __align__(16) f16 As[3][128 * 32];
  __shared__ __align__(16) f16 Bs[3][128 * 32];
  int tid = threadIdx.x, wid = tid >> 6, l = tid & 63;
  int lg = l >> 4, lr = l & 15;
  int nbx = gridDim.x;
  int flat = blockIdx.y * nbx + blockIdx.x;
  int xcd = flat & 7, idx = flat >> 3;
  int mc = nbx >> 3;
  int bm = (xcd * mc + idx % mc) * 128;
  int bn = (idx / mc) * 128;
  int wr = (wid >> 1) * 64, wc = (wid & 1) * 64;
  f32x4 acc[4][4] = {};

  int swz = ((l & 3) ^ ((l >> 3) & 3)) * 8;
  const f16* gA = A + (size_t)(bm + wid * 32 + (l >> 2)) * K + swz;
  const f16* gB = Bt + (size_t)(bn + wid * 32 + (l >> 2)) * K + swz;
  int lofs = wid * 32 * 32;
  int xr = (lr >> 1) & 3;

  f16* A0 = As[0]; f16* A1 = As[1]; f16* A2 = As[2];
  f16* B0 = Bs[0]; f16* B1 = Bs[1]; f16* B2 = Bs[2];

  #pragma unroll
  for (int ig = 0; ig < 2; ++ig) {
    gload16(gA + (size_t)(ig * 16) * K, A0 + lofs + ig * 16 * 32);
    gload16(gB + (size_t)(ig * 16) * K, B0 + lofs + ig * 16 * 32);
  }
  #pragma unroll
  for (int ig = 0; ig < 2; ++ig) {
    gload16(gA + (size_t)(ig * 16) * K + 32, A1 + lofs + ig * 16 * 32);
    gload16(gB + (size_t)(ig * 16) * K + 32, B1 + lofs + ig * 16 * 32);
  }

  int nt = K >> 5;
  for (int t = 0; t < nt; ++t) {
    if (t + 2 < nt) {
      int k2 = (t + 2) << 5;
      #pragma unroll
      for (int ig = 0; ig < 2; ++ig) {
        gload16(gA + (size_t)(ig * 16) * K + k2, A2 + lofs + ig * 16 * 32);
        gload16(gB + (size_t)(ig * 16) * K + k2, B2 + lofs + ig * 16 * 32);
      }
      asm volatile("s_waitcnt vmcnt(8)" ::: "memory");
    } else if (t + 2 == nt) {
      asm volatile("s_waitcnt vmcnt(4)" ::: "memory");
    } else {
      asm volatile("s_waitcnt vmcnt(0)" ::: "memory");
    }
    __builtin_amdgcn_s_barrier();

    f16x8 af[4], bf[4];
    #pragma unroll
    for (int i = 0; i < 4; ++i)
      af[i] = *(const f16x8*)(A0 + (wr + i * 16 + lr) * 32 + ((lg ^ xr) * 8));
    #pragma unroll
    for (int j = 0; j < 4; ++j)
      bf[j] = *(const f16x8*)(B0 + (wc + j * 16 + lr) * 32 + ((lg ^ xr) * 8));
    __builtin_amdgcn_s_setprio(1);
    #pragma unroll
    for (int i = 0; i < 4; ++i)
      #pragma unroll
      for (int j = 0; j < 4; ++j)
        acc[i][j] = __builtin_amdgcn_mfma_f32_16x16x32_f16(af[i], bf[j], acc[i][j], 0, 0, 0);
    __builtin_amdgcn_s_setprio(0);
    __builtin_amdgcn_sched_barrier(0);
    __builtin_amdgcn_s_barrier();

    f16* tA = A0; A0 = A1; A1 = A2; A2 = tA;
    f16* tB = B0; B0 = B1; B1 = B2; B2 = tB;
  }

  #pragma unroll
  for (int i = 0; i < 4; ++i) {
    #pragma unroll
    for (int j = 0; j < 4; ++j) {
      int n = bn + wc + j * 16 + lr;
      float bv = (EPI >= 1) ? bias[n] : 0.0f;
      #pragma unroll
      for (int r = 0; r < 4; ++r) {
        int m = bm + wr + i * 16 + lg * 4 + r;
        float v = acc[i][j][r];
        if (EPI == 0) {
          int bb = m >> 9, ss = m & 511;
          int which = n >> 10, c = n & 1023, hh = c >> 6, dd = c & 63;
          size_t base = (size_t)(bb * 16 + hh);
          if (which == 0)      Qo[(base * 512 + ss) * 64 + dd] = (f16)v;
          else if (which == 1) Ko[(base * 512 + ss) * 64 + dd] = (f16)v;
          else                 Vto[(base * 64 + dd) * 512 + ss] = (f16)v;
        } else if (EPI == 1) {
          v += bv;
          v = 0.5f * v * (1.0f + erff(v * 0.70710678118654752f));
          outH[(size_t)m * N + n] = (f16)v;
        } else if (EPI == 2) {
          v += bv + (float)resid[(size_t)m * N + n];
          outH[(size_t)m * N + n] = (f16)v;
        } else {
          outF[(size_t)m * N + n] = v + bv;
        }
      }
    }
  }
}

// ---------------------------------------------------------------------------
// gemm64: 64x64 tile, BK=64, 4 waves (2x2 of 32x32), 8 MFMA/step.
// Grid M/64 x N/64 = 1024 blocks -> 4 blocks/CU = 16 waves/CU (4x the TLP of
// the old 128x128 fc config). 2-buffer counted-vmcnt(4), prefetch distance 2.
// 128B LDS rows, swizzle chunk^=row&7 (8 chunks x 8 lanes = minimum aliasing,
// conflict-free); source pre-swizzle (l&7)^(l>>3) is the matching involution.
// ---------------------------------------------------------------------------
template <int EPI>
__global__ __launch_bounds__(256, 4) void gemm64(
    const f16* __restrict__ A, const f16* __restrict__ Bt,
    int M, int N, int K,
    const float* __restrict__ bias, const f16* __restrict__ resid,
    f16* __restrict__ outH, float* __restrict__ outF)
{
  __shared__ __align__(16) f16 As[2][64 * 64];
  __shared__ __align__(16) f16 Bs[2][64 * 64];
  int tid = threadIdx.x, wid = tid >> 6, l = tid & 63;
  int lg = l >> 4, lr = l & 15;
  int nbx = gridDim.x;
  int flat = blockIdx.y * nbx + blockIdx.x;
  int xcd = flat & 7, idx = flat >> 3;
  int mc = nbx >> 3;
  int bm = (xcd * mc + idx % mc) * 64;
  int bn = (idx / mc) * 64;
  int wr = (wid >> 1) * 32, wc = (wid & 1) * 32;
  f32x4 acc[2][2] = {};

  int srow = l >> 3;
  int swz = ((l & 7) ^ srow) * 8;              // source chunk involution
  const f16* gA = A + (size_t)(bm + wid * 16 + srow) * K + swz;
  const f16* gB = Bt + (size_t)(bn + wid * 16 + srow) * K + swz;
  int lofs = wid * 16 * 64;                    // wave stages 16 rows of each
  int xr = lr & 7;                             // read-side XOR (row&7 = lr&7)

  // prologue: stage tiles 0,1 (4 gloads/wave each)
  #pragma unroll
  for (int ig = 0; ig < 2; ++ig) {
    gload16(gA + (size_t)(ig * 8) * K, As[0] + lofs + ig * 8 * 64);
    gload16(gB + (size_t)(ig * 8) * K, Bs[0] + lofs + ig * 8 * 64);
  }
  #pragma unroll
  for (int ig = 0; ig < 2; ++ig) {
    gload16(gA + (size_t)(ig * 8) * K + 64, As[1] + lofs + ig * 8 * 64);
    gload16(gB + (size_t)(ig * 8) * K + 64, Bs[1] + lofs + ig * 8 * 64);
  }

  int nt = K >> 6;
  for (int t = 0; t < nt; ++t) {
    if (t < nt - 1) asm volatile("s_waitcnt vmcnt(4)" ::: "memory");
    else            asm volatile("s_waitcnt vmcnt(0)" ::: "memory");
    __builtin_amdgcn_s_barrier();
    __builtin_amdgcn_sched_barrier(0);

    const f16* Ac = As[t & 1];
    const f16* Bc = Bs[t & 1];
    f16x8 af[2][2], bf[2][2];
    #pragma unroll
    for (int kk = 0; kk < 2; ++kk) {
      #pragma unroll
      for (int i = 0; i < 2; ++i)
        af[kk][i] = *(const f16x8*)(Ac + (wr + i * 16 + lr) * 64 + (((kk * 4 + lg) ^ xr) * 8));
      #pragma unroll
      for (int j = 0; j < 2; ++j)
        bf[kk][j] = *(const f16x8*)(Bc + (wc + j * 16 + lr) * 64 + (((kk * 4 + lg) ^ xr) * 8));
    }
    __builtin_amdgcn_s_setprio(1);
    #pragma unroll
    for (int kk = 0; kk < 2; ++kk)
      #pragma unroll
      for (int i = 0; i < 2; ++i)
        #pragma unroll
        for (int j = 0; j < 2; ++j)
          acc[i][j] = __builtin_amdgcn_mfma_f32_16x16x32_f16(af[kk][i], bf[kk][j], acc[i][j], 0, 0, 0);
    __builtin_amdgcn_s_setprio(0);
    __builtin_amdgcn_sched_barrier(0);
    __builtin_amdgcn_s_barrier();
    __builtin_amdgcn_sched_barrier(0);
    if (t + 2 < nt) {
      int k2 = (t + 2) << 6;
      #pragma unroll
      for (int ig = 0; ig < 2; ++ig) {
        gload16(gA + (size_t)(ig * 8) * K + k2, As[t & 1] + lofs + ig * 8 * 64);
        gload16(gB + (size_t)(ig * 8) * K + k2, Bs[t & 1] + lofs + ig * 8 * 64);
      }
    }
  }

  #pragma unroll
  for (int i = 0; i < 2; ++i) {
    #pragma unroll
    for (int j = 0; j < 2; ++j) {
      int n = bn + wc + j * 16 + lr;
      float bv = bias[n];
      #pragma unroll
      for (int r = 0; r < 4; ++r) {
        int m = bm + wr + i * 16 + lg * 4 + r;
        float v = acc[i][j][r];
        if (EPI == 1) {
          v += bv;
          v = 0.5f * v * (1.0f + erff(v * 0.70710678118654752f));
          outH[(size_t)m * N + n] = (f16)v;
        } else if (EPI == 2) {
          v += bv + (float)resid[(size_t)m * N + n];
          outH[(size_t)m * N + n] = (f16)v;
        } else {
          outF[(size_t)m * N + n] = v + bv;
        }
      }
    }
  }
}

// ---------------------------------------------------------------------------
// Flash attention: as R5 but Ps halved (per-wave 16x128, PV split per i-half)
// -> LDS 48KB -> 3 blocks/CU (was 2). V-frags re-read per half (cheap).
// ---------------------------------------------------------------------------
__global__ __launch_bounds__(256) void attn_kernel(
    const f16* __restrict__ Q, const f16* __restrict__ Kc,
    const f16* __restrict__ Vt, const unsigned char* __restrict__ cmask,
    f16* __restrict__ XO)
{
  __shared__ __align__(16) f16 Ks[128 * 64];
  __shared__ __align__(16) f16 Vs[64 * 128];
  __shared__ __align__(16) f16 Ps[4 * 16 * 128];   // 16KB (was 32KB)
  int tid = threadIdx.x, w = tid >> 6, l = tid & 63;
  int lg = l >> 4, lr = l & 15;
  int flat = blockIdx.y * 4 + blockIdx.x;
  flat = (flat & 7) * 64 + (flat >> 3);
  int qblk = flat & 3, bh = flat >> 2;
  int b = bh >> 4, h = bh & 15;
  const f16* Qg = Q + (size_t)bh * 512 * 64 + qblk * 128 * 64;
  const f16* Kg = Kc + (size_t)bh * 512 * 64;
  const f16* Vg = Vt + (size_t)bh * 64 * 512;
  const unsigned char* mb = cmask + b * 512;

  f16x8 qf[2][2];
  #pragma unroll
  for (int i = 0; i < 2; ++i)
    #pragma unroll
    for (int kc = 0; kc < 2; ++kc)
      qf[i][kc] = *(const f16x8*)(Qg + (size_t)(w * 32 + i * 16 + lr) * 64 + kc * 32 + lg * 8);

  f32x4 O[2][4] = {};
  float mrow[2][4], lrow[2][4];
  #pragma unroll
  for (int i = 0; i < 2; ++i)
    #pragma unroll
    for (int r = 0; r < 4; ++r) { mrow[i][r] = -1e30f; lrow[i][r] = 0.0f; }

  f16* Pw = Ps + w * 16 * 128;

  int kR = tid >> 3, kC = (tid & 7) * 8;
  int vR = tid >> 4, vC = (tid & 15) * 8;
  f16x8 kreg[4], vreg[4];
  #pragma unroll
  for (int i = 0; i < 4; ++i) {
    kreg[i] = *(const f16x8*)(Kg + (size_t)(i * 32 + kR) * 64 + kC);
    vreg[i] = *(const f16x8*)(Vg + (size_t)(i * 16 + vR) * 512 + vC);
  }

  for (int kt = 0; kt < 4; ++kt) {
    #pragma unroll
    for (int i = 0; i < 4; ++i) {
      int krow = i * 32 + kR;
      *(f16x8*)(Ks + krow * 64 + (((tid & 7) ^ (krow & 7)) * 8)) = kreg[i];
      int vrow = i * 16 + vR;
      *(f16x8*)(Vs + vrow * 128 + (((tid & 15) ^ (vrow & 7)) * 8)) = vreg[i];
    }
    __syncthreads();
    if (kt < 3) {
      #pragma unroll
      for (int i = 0; i < 4; ++i) {
        kreg[i] = *(const f16x8*)(Kg + (size_t)((kt + 1) * 128 + i * 32 + kR) * 64 + kC);
        vreg[i] = *(const f16x8*)(Vg + (size_t)(i * 16 + vR) * 512 + (kt + 1) * 128 + vC);
      }
    }

    int x = lr & 7;
    f32x4 sc[2][8] = {};
    __builtin_amdgcn_s_setprio(1);
    #pragma unroll
    for (int j = 0; j < 8; ++j) {
      const f16* krow = Ks + (j * 16 + lr) * 64;
      f16x8 kf0 = *(const f16x8*)(krow + ((lg ^ x) * 8));
      f16x8 kf1 = *(const f16x8*)(krow + (((4 + lg) ^ x) * 8));
      sc[0][j] = __builtin_amdgcn_mfma_f32_16x16x32_f16(qf[0][0], kf0, sc[0][j], 0, 0, 0);
      sc[0][j] = __builtin_amdgcn_mfma_f32_16x16x32_f16(qf[0][1], kf1, sc[0][j], 0, 0, 0);
      sc[1][j] = __builtin_amdgcn_mfma_f32_16x16x32_f16(qf[1][0], kf0, sc[1][j], 0, 0, 0);
      sc[1][j] = __builtin_amdgcn_mfma_f32_16x16x32_f16(qf[1][1], kf1, sc[1][j], 0, 0, 0);
    }
    __builtin_amdgcn_s_setprio(0);
    bool keep[8];
    #pragma unroll
    for (int j = 0; j < 8; ++j) keep[j] = mb[kt * 128 + j * 16 + lr] != 0;
    #pragma unroll
    for (int i = 0; i < 2; ++i)
      #pragma unroll
      for (int j = 0; j < 8; ++j)
        #pragma unroll
        for (int r = 0; r < 4; ++r)
          sc[i][j][r] = keep[j] ? sc[i][j][r] : -1e30f;

    #pragma unroll
    for (int i = 0; i < 2; ++i) {
      #pragma unroll
      for (int r = 0; r < 4; ++r) {
        float pm = sc[i][0][r];
        #pragma unroll
        for (int j = 1; j < 8; ++j) pm = fmaxf(pm, sc[i][j][r]);
        pm = fmaxf(pm, __shfl_xor(pm, 1));
        pm = fmaxf(pm, __shfl_xor(pm, 2));
        pm = fmaxf(pm, __shfl_xor(pm, 4));
        pm = fmaxf(pm, __shfl_xor(pm, 8));
        float mn = fmaxf(mrow[i][r], pm);
        float alpha = __expf(mrow[i][r] - mn);
        mrow[i][r] = mn;
        lrow[i][r] *= alpha;
        #pragma unroll
        for (int jd = 0; jd < 4; ++jd) O[i][jd][r] *= alpha;
      }
    }
    // per i-half: write P (16 rows), row-sum, PV for this half, then reuse Pw
    #pragma unroll
    for (int i = 0; i < 2; ++i) {
      float rs[4] = {0.f, 0.f, 0.f, 0.f};
      #pragma unroll
      for (int j = 0; j < 8; ++j)
        #pragma unroll
        for (int r = 0; r < 4; ++r) {
          float p = __expf(sc[i][j][r] - mrow[i][r]);
          rs[r] += p;
          int prow = lg * 4 + r;
          int pc = j * 16 + lr;
          Pw[prow * 128 + ((((pc >> 3) ^ (prow & 7)) << 3) | (pc & 7))] = (f16)p;
        }
      #pragma unroll
      for (int r = 0; r < 4; ++r) {
        float s = rs[r];
        s += __shfl_xor(s, 1); s += __shfl_xor(s, 2);
        s += __shfl_xor(s, 4); s += __shfl_xor(s, 8);
        lrow[i][r] += s;
      }
      __builtin_amdgcn_s_setprio(1);
      #pragma unroll
      for (int kk = 0; kk < 4; ++kk) {
        int c0 = ((kk * 4 + lg) ^ x) * 8;
        f16x8 pa = *(const f16x8*)(Pw + lr * 128 + c0);
        #pragma unroll
        for (int jd = 0; jd < 4; ++jd) {
          f16x8 vb = *(const f16x8*)(Vs + (jd * 16 + lr) * 128 + c0);
          O[i][jd] = __builtin_amdgcn_mfma_f32_16x16x32_f16(pa, vb, O[i][jd], 0, 0, 0);
        }
      }
      __builtin_amdgcn_s_setprio(0);
    }
    __syncthreads();
  }

  #pragma unroll
  for (int i = 0; i < 2; ++i)
    #pragma unroll
    for (int r = 0; r < 4; ++r) {
      int q = qblk * 128 + w * 32 + i * 16 + lg * 4 + r;
      float inv = 1.0f / lrow[i][r];
      #pragma unroll
      for (int jd = 0; jd < 4; ++jd) {
        int c = h * 64 + jd * 16 + lr;
        XO[((size_t)b * 512 + q) * 1024 + c] = (f16)(O[i][jd][r] * inv);
      }
    }
}

// ---------------------------------------------------------------------------
extern "C" void kernel_launch(void* const* d_in, const int* in_sizes, int n_in,
                              void* d_out, int out_size, void* d_ws, size_t ws_size,
                              hipStream_t stream)
{
  (void)in_sizes; (void)n_in; (void)out_size; (void)ws_size;
  const float* x            = (const float*)d_in[0];
  const unsigned char* mask = (const unsigned char*)d_in[1];
  const float* qkv_w   = (const float*)d_in[2];
  const float* qkv_la  = (const float*)d_in[3];
  const float* qkv_lb  = (const float*)d_in[4];
  const float* proj_w  = (const float*)d_in[5];
  const float* proj_b  = (const float*)d_in[6];
  const float* proj_la = (const float*)d_in[7];
  const float* proj_lb = (const float*)d_in[8];
  const float* fc1_w   = (const float*)d_in[9];
  const float* fc1_b   = (const float*)d_in[10];
  const float* fc1_la  = (const float*)d_in[11];
  const float* fc1_lb  = (const float*)d_in[12];
  const float* fc2_w   = (const float*)d_in[13];
  const float* fc2_b   = (const float*)d_in[14];
  const float* fc2_la  = (const float*)d_in[15];
  const float* fc2_lb  = (const float*)d_in[16];
  float* out = (float*)d_out;

  f16* p = (f16*)d_ws;
  f16* WqkvT = p; p += 3072 * 1024;
  f16* W1T   = p; p += 1024 * 1024;
  f16* W2T   = p; p += 1024 * 1024;
  f16* WpT   = p; p += 1024 * 1024;
  f16* Xh    = p; p += 4096 * 1024;
  f16* Qb    = p; p += 128 * 512 * 64;
  f16* Kb    = p; p += 128 * 512 * 64;
  f16* Vt    = p; p += 128 * 64 * 512;
  f16* XO    = p; p += 4096 * 1024;
  unsigned char* cmask = (unsigned char*)p;
  f16* Hb  = Qb;
  f16* XO2 = Xh;

  weff3<<<dim3(48, 16), 256, 0, stream>>>(qkv_w, qkv_la, qkv_lb, WqkvT, 3072, 1024, 1024);
  weff3<<<dim3(16, 16), 256, 0, stream>>>(fc1_w, fc1_la, fc1_lb, W1T, 1024, 1024, 0);
  weff3<<<dim3(16, 16), 256, 0, stream>>>(fc2_w, fc2_la, fc2_lb, W2T, 1024, 1024, 0);
  weff3<<<dim3(16, 16), 256, 0, stream>>>(proj_w, proj_la, proj_lb, WpT, 1024, 1024, 0);
  cvt_f32_f16<<<4096, 256, 0, stream>>>(x, Xh);
  mask_canon<<<1, 256, 0, stream>>>(mask, cmask);

  gemmk<0><<<dim3(32, 24), 256, 0, stream>>>(Xh, WqkvT, 4096, 3072, 1024,
      nullptr, nullptr, nullptr, nullptr, Qb, Kb, Vt);
  attn_kernel<<<dim3(4, 128), 256, 0, stream>>>(Qb, Kb, Vt, cmask, XO);
  gemm64<1><<<dim3(64, 16), 256, 0, stream>>>(XO, W1T, 4096, 1024, 1024,
      fc1_b, nullptr, Hb, nullptr);
  gemm64<2><<<dim3(64, 16), 256, 0, stream>>>(Hb, W2T, 4096, 1024, 1024,
      fc2_b, XO, XO2, nullptr);
  gemm64<3><<<dim3(64, 16), 256, 0, stream>>>(XO2, WpT, 4096, 1024, 1024,
      proj_b, nullptr, nullptr, out);
}

// Round 7
// 273.212 us; speedup vs baseline: 1.0740x; 1.0361x over previous
//
#include <hip/hip_runtime.h>

typedef _Float16 f16;
typedef _Float16 f16x8 __attribute__((ext_vector_type(8)));
typedef _Float16 f16x4v __attribute__((ext_vector_type(4)));
typedef float f32x4 __attribute__((ext_vector_type(4)));

#define DEVINL __device__ __forceinline__

DEVINL void gload16(const void* g, void* l) {
  __builtin_amdgcn_global_load_lds(
      (const __attribute__((address_space(1))) void*)g,
      (__attribute__((address_space(3))) void*)l, 16, 0, 0);
}

// ---------------------------------------------------------------------------
// prep_all: ONE dispatch for all preprocessing (was 6 dispatches).
//   blocks [0,1536)      : weff tiles (qkv 768, fc1 256, fc2 256, proj 256)
//   blocks [1536,3584)   : x fp32->fp16 conversion (8 floats/thread)
//   block  3584          : mask canonicalization
// weff: WT[n][k] = (W[k][n] + la[k][:]·lb[:][n]) * scale, 64n x 64k tile.
// ---------------------------------------------------------------------------
__device__ void weff_body(const float* __restrict__ W, const float* __restrict__ la,
                          const float* __restrict__ lb, f16* __restrict__ WT,
                          int N, int K, int scaleCols, int n0, int k0,
                          float (*La)[36], f16 (*Ts)[72])
{
  int t = threadIdx.x;
  int w = t >> 6, nn = t & 63;
  #pragma unroll
  for (int i = 0; i < 8; ++i) {
    int idx = i * 256 + t;
    int row = idx >> 5, r = idx & 31;
    La[row][r] = la[(size_t)(k0 + row) * 32 + r];
  }
  float lbr[32];
  #pragma unroll
  for (int r = 0; r < 32; ++r) lbr[r] = lb[(size_t)r * N + n0 + nn];
  float scale = (n0 + nn < scaleCols) ? 0.125f : 1.0f;
  __syncthreads();
  float prev = 0.0f;
  #pragma unroll
  for (int i = 0; i < 16; ++i) {
    int k = w * 16 + i;
    float acc = W[(size_t)(k0 + k) * N + n0 + nn];
    #pragma unroll
    for (int rc = 0; rc < 8; ++rc) {
      float4 a4 = *(const float4*)&La[k][rc * 4];
      acc += a4.x * lbr[rc * 4] + a4.y * lbr[rc * 4 + 1] +
             a4.z * lbr[rc * 4 + 2] + a4.w * lbr[rc * 4 + 3];
    }
    acc *= scale;
    if (i & 1) {
      union { f16 h[2]; unsigned u; } pk;
      pk.h[0] = (f16)prev; pk.h[1] = (f16)acc;
      *(unsigned*)&Ts[nn][k - 1] = pk.u;
    } else prev = acc;
  }
  __syncthreads();
  #pragma unroll
  for (int it = 0; it < 2; ++it) {
    int id = it * 256 + t;
    int row = id >> 3, c8 = id & 7;
    f16x8 h = *(const f16x8*)&Ts[row][c8 * 8];
    *(f16x8*)(WT + (size_t)(n0 + row) * K + k0 + c8 * 8) = h;
  }
}

__global__ __launch_bounds__(256) void prep_all(
    const float* __restrict__ x, const unsigned char* __restrict__ mask,
    const float* __restrict__ qkv_w, const float* __restrict__ qkv_la, const float* __restrict__ qkv_lb,
    const float* __restrict__ fc1_w, const float* __restrict__ fc1_la, const float* __restrict__ fc1_lb,
    const float* __restrict__ fc2_w, const float* __restrict__ fc2_la, const float* __restrict__ fc2_lb,
    const float* __restrict__ proj_w, const float* __restrict__ proj_la, const float* __restrict__ proj_lb,
    f16* __restrict__ WqkvT, f16* __restrict__ W1T, f16* __restrict__ W2T, f16* __restrict__ WpT,
    f16* __restrict__ Xh, unsigned char* __restrict__ cmask)
{
  __shared__ float La[64][36];
  __shared__ f16 Ts[64][72];
  int bid = blockIdx.x;
  int t = threadIdx.x;
  if (bid < 1536) {
    if (bid < 768) {
      weff_body(qkv_w, qkv_la, qkv_lb, WqkvT, 3072, 1024, 1024,
                (bid % 48) * 64, (bid / 48) * 64, La, Ts);
    } else if (bid < 1024) {
      int tt = bid - 768;
      weff_body(fc1_w, fc1_la, fc1_lb, W1T, 1024, 1024, 0,
                (tt & 15) * 64, (tt >> 4) * 64, La, Ts);
    } else if (bid < 1280) {
      int tt = bid - 1024;
      weff_body(fc2_w, fc2_la, fc2_lb, W2T, 1024, 1024, 0,
                (tt & 15) * 64, (tt >> 4) * 64, La, Ts);
    } else {
      int tt = bid - 1280;
      weff_body(proj_w, proj_la, proj_lb, WpT, 1024, 1024, 0,
                (tt & 15) * 64, (tt >> 4) * 64, La, Ts);
    }
  } else if (bid < 3584) {
    size_t i = ((size_t)(bid - 1536) * 256 + t) * 8;
    float4 v0 = *(const float4*)(x + i);
    float4 v1 = *(const float4*)(x + i + 4);
    f16x8 o = {(f16)v0.x, (f16)v0.y, (f16)v0.z, (f16)v0.w,
               (f16)v1.x, (f16)v1.y, (f16)v1.z, (f16)v1.w};
    *(f16x8*)(Xh + i) = o;
  } else {
    __shared__ int flag;
    if (t == 0) flag = 0;
    __syncthreads();
    int found = 0;
    for (int p = t; p < 12288; p += 256)
      if ((p & 3) && mask[p]) found = 1;
    if (found) flag = 1;
    __syncthreads();
    int u8 = flag;
    const int* mi = (const int*)mask;
    for (int idx = t; idx < 4096; idx += 256) {
      int b = idx >> 9, k = idx & 511;
      int v = u8 ? (int)mask[b * 1536 + k] : mi[b * 1536 + k];
      cmask[idx] = (unsigned char)(v != 0);
    }
  }
}

// ---------------------------------------------------------------------------
// gemm0 (FROZEN from R5): 128x128, BK=32, 3-buffer counted vmcnt(8).
// ---------------------------------------------------------------------------
template <int EPI>
__global__ __launch_bounds__(256, 3) void gemmk(
    const f16* __restrict__ A, const f16* __restrict__ Bt,
    int M, int N, int K,
    const float* __restrict__ bias, const f16* __restrict__ resid,
    f16* __restrict__ outH, float* __restrict__ outF,
    f16* __restrict__ Qo, f16* __restrict__ Ko, f16* __restrict__ Vto)
{
  __shared__ __align__(16) f16 As[3][128 * 32];
  __shared__ __align__(16) f16 Bs[3][128 * 32];
  int tid = threadIdx.x, wid = tid >> 6, l = tid & 63;
  int lg = l >> 4, lr = l & 15;
  int nbx = gridDim.x;
  int flat = blockIdx.y * nbx + blockIdx.x;
  int xcd = flat & 7, idx = flat >> 3;
  int mc = nbx >> 3;
  int bm = (xcd * mc + idx % mc) * 128;
  int bn = (idx / mc) * 128;
  int wr = (wid >> 1) * 64, wc = (wid & 1) * 64;
  f32x4 acc[4][4] = {};

  int swz = ((l & 3) ^ ((l >> 3) & 3)) * 8;
  const f16* gA = A + (size_t)(bm + wid * 32 + (l >> 2)) * K + swz;
  const f16* gB = Bt + (size_t)(bn + wid * 32 + (l >> 2)) * K + swz;
  int lofs = wid * 32 * 32;
  int xr = (lr >> 1) & 3;

  f16* A0 = As[0]; f16* A1 = As[1]; f16* A2 = As[2];
  f16* B0 = Bs[0]; f16* B1 = Bs[1]; f16* B2 = Bs[2];

  #pragma unroll
  for (int ig = 0; ig < 2; ++ig) {
    gload16(gA + (size_t)(ig * 16) * K, A0 + lofs + ig * 16 * 32);
    gload16(gB + (size_t)(ig * 16) * K, B0 + lofs + ig * 16 * 32);
  }
  #pragma unroll
  for (int ig = 0; ig < 2; ++ig) {
    gload16(gA + (size_t)(ig * 16) * K + 32, A1 + lofs + ig * 16 * 32);
    gload16(gB + (size_t)(ig * 16) * K + 32, B1 + lofs + ig * 16 * 32);
  }

  int nt = K >> 5;
  for (int t = 0; t < nt; ++t) {
    if (t + 2 < nt) {
      int k2 = (t + 2) << 5;
      #pragma unroll
      for (int ig = 0; ig < 2; ++ig) {
        gload16(gA + (size_t)(ig * 16) * K + k2, A2 + lofs + ig * 16 * 32);
        gload16(gB + (size_t)(ig * 16) * K + k2, B2 + lofs + ig * 16 * 32);
      }
      asm volatile("s_waitcnt vmcnt(8)" ::: "memory");
    } else if (t + 2 == nt) {
      asm volatile("s_waitcnt vmcnt(4)" ::: "memory");
    } else {
      asm volatile("s_waitcnt vmcnt(0)" ::: "memory");
    }
    __builtin_amdgcn_s_barrier();

    f16x8 af[4], bf[4];
    #pragma unroll
    for (int i = 0; i < 4; ++i)
      af[i] = *(const f16x8*)(A0 + (wr + i * 16 + lr) * 32 + ((lg ^ xr) * 8));
    #pragma unroll
    for (int j = 0; j < 4; ++j)
      bf[j] = *(const f16x8*)(B0 + (wc + j * 16 + lr) * 32 + ((lg ^ xr) * 8));
    __builtin_amdgcn_s_setprio(1);
    #pragma unroll
    for (int i = 0; i < 4; ++i)
      #pragma unroll
      for (int j = 0; j < 4; ++j)
        acc[i][j] = __builtin_amdgcn_mfma_f32_16x16x32_f16(af[i], bf[j], acc[i][j], 0, 0, 0);
    __builtin_amdgcn_s_setprio(0);
    __builtin_amdgcn_sched_barrier(0);
    __builtin_amdgcn_s_barrier();

    f16* tA = A0; A0 = A1; A1 = A2; A2 = tA;
    f16* tB = B0; B0 = B1; B1 = B2; B2 = tB;
  }

  #pragma unroll
  for (int i = 0; i < 4; ++i) {
    #pragma unroll
    for (int j = 0; j < 4; ++j) {
      int n = bn + wc + j * 16 + lr;
      float bv = (EPI >= 1) ? bias[n] : 0.0f;
      #pragma unroll
      for (int r = 0; r < 4; ++r) {
        int m = bm + wr + i * 16 + lg * 4 + r;
        float v = acc[i][j][r];
        if (EPI == 0) {
          int bb = m >> 9, ss = m & 511;
          int which = n >> 10, c = n & 1023, hh = c >> 6, dd = c & 63;
          size_t base = (size_t)(bb * 16 + hh);
          if (which == 0)      Qo[(base * 512 + ss) * 64 + dd] = (f16)v;
          else if (which == 1) Ko[(base * 512 + ss) * 64 + dd] = (f16)v;
          else                 Vto[(base * 64 + dd) * 512 + ss] = (f16)v;
        } else if (EPI == 1) {
          v += bv;
          v = 0.5f * v * (1.0f + erff(v * 0.70710678118654752f));
          outH[(size_t)m * N + n] = (f16)v;
        } else if (EPI == 2) {
          v += bv + (float)resid[(size_t)m * N + n];
          outH[(size_t)m * N + n] = (f16)v;
        } else {
          outF[(size_t)m * N + n] = v + bv;
        }
      }
    }
  }
}

// ---------------------------------------------------------------------------
// gemm64 (FROZEN from R6): 64x64 tile, BK=64, 2-buffer counted vmcnt(4).
// ---------------------------------------------------------------------------
template <int EPI>
__global__ __launch_bounds__(256, 4) void gemm64(
    const f16* __restrict__ A, const f16* __restrict__ Bt,
    int M, int N, int K,
    const float* __restrict__ bias, const f16* __restrict__ resid,
    f16* __restrict__ outH, float* __restrict__ outF)
{
  __shared__ __align__(16) f16 As[2][64 * 64];
  __shared__ __align__(16) f16 Bs[2][64 * 64];
  int tid = threadIdx.x, wid = tid >> 6, l = tid & 63;
  int lg = l >> 4, lr = l & 15;
  int nbx = gridDim.x;
  int flat = blockIdx.y * nbx + blockIdx.x;
  int xcd = flat & 7, idx = flat >> 3;
  int mc = nbx >> 3;
  int bm = (xcd * mc + idx % mc) * 64;
  int bn = (idx / mc) * 64;
  int wr = (wid >> 1) * 32, wc = (wid & 1) * 32;
  f32x4 acc[2][2] = {};

  int srow = l >> 3;
  int swz = ((l & 7) ^ srow) * 8;
  const f16* gA = A + (size_t)(bm + wid * 16 + srow) * K + swz;
  const f16* gB = Bt + (size_t)(bn + wid * 16 + srow) * K + swz;
  int lofs = wid * 16 * 64;
  int xr = lr & 7;

  #pragma unroll
  for (int ig = 0; ig < 2; ++ig) {
    gload16(gA + (size_t)(ig * 8) * K, As[0] + lofs + ig * 8 * 64);
    gload16(gB + (size_t)(ig * 8) * K, Bs[0] + lofs + ig * 8 * 64);
  }
  #pragma unroll
  for (int ig = 0; ig < 2; ++ig) {
    gload16(gA + (size_t)(ig * 8) * K + 64, As[1] + lofs + ig * 8 * 64);
    gload16(gB + (size_t)(ig * 8) * K + 64, Bs[1] + lofs + ig * 8 * 64);
  }

  int nt = K >> 6;
  for (int t = 0; t < nt; ++t) {
    if (t < nt - 1) asm volatile("s_waitcnt vmcnt(4)" ::: "memory");
    else            asm volatile("s_waitcnt vmcnt(0)" ::: "memory");
    __builtin_amdgcn_s_barrier();
    __builtin_amdgcn_sched_barrier(0);

    const f16* Ac = As[t & 1];
    const f16* Bc = Bs[t & 1];
    f16x8 af[2][2], bf[2][2];
    #pragma unroll
    for (int kk = 0; kk < 2; ++kk) {
      #pragma unroll
      for (int i = 0; i < 2; ++i)
        af[kk][i] = *(const f16x8*)(Ac + (wr + i * 16 + lr) * 64 + (((kk * 4 + lg) ^ xr) * 8));
      #pragma unroll
      for (int j = 0; j < 2; ++j)
        bf[kk][j] = *(const f16x8*)(Bc + (wc + j * 16 + lr) * 64 + (((kk * 4 + lg) ^ xr) * 8));
    }
    __builtin_amdgcn_s_setprio(1);
    #pragma unroll
    for (int kk = 0; kk < 2; ++kk)
      #pragma unroll
      for (int i = 0; i < 2; ++i)
        #pragma unroll
        for (int j = 0; j < 2; ++j)
          acc[i][j] = __builtin_amdgcn_mfma_f32_16x16x32_f16(af[kk][i], bf[kk][j], acc[i][j], 0, 0, 0);
    __builtin_amdgcn_s_setprio(0);
    __builtin_amdgcn_sched_barrier(0);
    __builtin_amdgcn_s_barrier();
    __builtin_amdgcn_sched_barrier(0);
    if (t + 2 < nt) {
      int k2 = (t + 2) << 6;
      #pragma unroll
      for (int ig = 0; ig < 2; ++ig) {
        gload16(gA + (size_t)(ig * 8) * K + k2, As[t & 1] + lofs + ig * 8 * 64);
        gload16(gB + (size_t)(ig * 8) * K + k2, Bs[t & 1] + lofs + ig * 8 * 64);
      }
    }
  }

  #pragma unroll
  for (int i = 0; i < 2; ++i) {
    #pragma unroll
    for (int j = 0; j < 2; ++j) {
      int n = bn + wc + j * 16 + lr;
      float bv = bias[n];
      #pragma unroll
      for (int r = 0; r < 4; ++r) {
        int m = bm + wr + i * 16 + lg * 4 + r;
        float v = acc[i][j][r];
        if (EPI == 1) {
          v += bv;
          v = 0.5f * v * (1.0f + erff(v * 0.70710678118654752f));
          outH[(size_t)m * N + n] = (f16)v;
        } else if (EPI == 2) {
          v += bv + (float)resid[(size_t)m * N + n];
          outH[(size_t)m * N + n] = (f16)v;
        } else {
          outF[(size_t)m * N + n] = v + bv;
        }
      }
    }
  }
}

// ---------------------------------------------------------------------------
// Flash attention (R6 structure; mask folded into MFMA C-init as -1e30 bias,
// removing the per-element cndmask pass).
// ---------------------------------------------------------------------------
__global__ __launch_bounds__(256) void attn_kernel(
    const f16* __restrict__ Q, const f16* __restrict__ Kc,
    const f16* __restrict__ Vt, const unsigned char* __restrict__ cmask,
    f16* __restrict__ XO)
{
  __shared__ __align__(16) f16 Ks[128 * 64];
  __shared__ __align__(16) f16 Vs[64 * 128];
  __shared__ __align__(16) f16 Ps[4 * 16 * 128];
  int tid = threadIdx.x, w = tid >> 6, l = tid & 63;
  int lg = l >> 4, lr = l & 15;
  int flat = blockIdx.y * 4 + blockIdx.x;
  flat = (flat & 7) * 64 + (flat >> 3);
  int qblk = flat & 3, bh = flat >> 2;
  int b = bh >> 4, h = bh & 15;
  const f16* Qg = Q + (size_t)bh * 512 * 64 + qblk * 128 * 64;
  const f16* Kg = Kc + (size_t)bh * 512 * 64;
  const f16* Vg = Vt + (size_t)bh * 64 * 512;
  const unsigned char* mb = cmask + b * 512;

  f16x8 qf[2][2];
  #pragma unroll
  for (int i = 0; i < 2; ++i)
    #pragma unroll
    for (int kc = 0; kc < 2; ++kc)
      qf[i][kc] = *(const f16x8*)(Qg + (size_t)(w * 32 + i * 16 + lr) * 64 + kc * 32 + lg * 8);

  f32x4 O[2][4] = {};
  float mrow[2][4], lrow[2][4];
  #pragma unroll
  for (int i = 0; i < 2; ++i)
    #pragma unroll
    for (int r = 0; r < 4; ++r) { mrow[i][r] = -1e30f; lrow[i][r] = 0.0f; }

  f16* Pw = Ps + w * 16 * 128;

  int kR = tid >> 3, kC = (tid & 7) * 8;
  int vR = tid >> 4, vC = (tid & 15) * 8;
  f16x8 kreg[4], vreg[4];
  #pragma unroll
  for (int i = 0; i < 4; ++i) {
    kreg[i] = *(const f16x8*)(Kg + (size_t)(i * 32 + kR) * 64 + kC);
    vreg[i] = *(const f16x8*)(Vg + (size_t)(i * 16 + vR) * 512 + vC);
  }

  for (int kt = 0; kt < 4; ++kt) {
    #pragma unroll
    for (int i = 0; i < 4; ++i) {
      int krow = i * 32 + kR;
      *(f16x8*)(Ks + krow * 64 + (((tid & 7) ^ (krow & 7)) * 8)) = kreg[i];
      int vrow = i * 16 + vR;
      *(f16x8*)(Vs + vrow * 128 + (((tid & 15) ^ (vrow & 7)) * 8)) = vreg[i];
    }
    __syncthreads();
    if (kt < 3) {
      #pragma unroll
      for (int i = 0; i < 4; ++i) {
        kreg[i] = *(const f16x8*)(Kg + (size_t)((kt + 1) * 128 + i * 32 + kR) * 64 + kC);
        vreg[i] = *(const f16x8*)(Vg + (size_t)(i * 16 + vR) * 512 + (kt + 1) * 128 + vC);
      }
    }

    int x = lr & 7;
    // mask folded into C-init: bias -1e30 on masked k-columns (col = lr)
    f32x4 sc[2][8];
    #pragma unroll
    for (int j = 0; j < 8; ++j) {
      float bj = mb[kt * 128 + j * 16 + lr] ? 0.0f : -1e30f;
      f32x4 binit = {bj, bj, bj, bj};
      sc[0][j] = binit;
      sc[1][j] = binit;
    }
    __builtin_amdgcn_s_setprio(1);
    #pragma unroll
    for (int j = 0; j < 8; ++j) {
      const f16* krow = Ks + (j * 16 + lr) * 64;
      f16x8 kf0 = *(const f16x8*)(krow + ((lg ^ x) * 8));
      f16x8 kf1 = *(const f16x8*)(krow + (((4 + lg) ^ x) * 8));
      sc[0][j] = __builtin_amdgcn_mfma_f32_16x16x32_f16(qf[0][0], kf0, sc[0][j], 0, 0, 0);
      sc[0][j] = __builtin_amdgcn_mfma_f32_16x16x32_f16(qf[0][1], kf1, sc[0][j], 0, 0, 0);
      sc[1][j] = __builtin_amdgcn_mfma_f32_16x16x32_f16(qf[1][0], kf0, sc[1][j], 0, 0, 0);
      sc[1][j] = __builtin_amdgcn_mfma_f32_16x16x32_f16(qf[1][1], kf1, sc[1][j], 0, 0, 0);
    }
    __builtin_amdgcn_s_setprio(0);

    #pragma unroll
    for (int i = 0; i < 2; ++i) {
      #pragma unroll
      for (int r = 0; r < 4; ++r) {
        float pm = sc[i][0][r];
        #pragma unroll
        for (int j = 1; j < 8; ++j) pm = fmaxf(pm, sc[i][j][r]);
        pm = fmaxf(pm, __shfl_xor(pm, 1));
        pm = fmaxf(pm, __shfl_xor(pm, 2));
        pm = fmaxf(pm, __shfl_xor(pm, 4));
        pm = fmaxf(pm, __shfl_xor(pm, 8));
        float mn = fmaxf(mrow[i][r], pm);
        float alpha = __expf(mrow[i][r] - mn);
        mrow[i][r] = mn;
        lrow[i][r] *= alpha;
        #pragma unroll
        for (int jd = 0; jd < 4; ++jd) O[i][jd][r] *= alpha;
      }
    }
    #pragma unroll
    for (int i = 0; i < 2; ++i) {
      float rs[4] = {0.f, 0.f, 0.f, 0.f};
      #pragma unroll
      for (int j = 0; j < 8; ++j)
        #pragma unroll
        for (int r = 0; r < 4; ++r) {
          float p = __expf(sc[i][j][r] - mrow[i][r]);
          rs[r] += p;
          int prow = lg * 4 + r;
          int pc = j * 16 + lr;
          Pw[prow * 128 + ((((pc >> 3) ^ (prow & 7)) << 3) | (pc & 7))] = (f16)p;
        }
      #pragma unroll
      for (int r = 0; r < 4; ++r) {
        float s = rs[r];
        s += __shfl_xor(s, 1); s += __shfl_xor(s, 2);
        s += __shfl_xor(s, 4); s += __shfl_xor(s, 8);
        lrow[i][r] += s;
      }
      __builtin_amdgcn_s_setprio(1);
      #pragma unroll
      for (int kk = 0; kk < 4; ++kk) {
        int c0 = ((kk * 4 + lg) ^ x) * 8;
        f16x8 pa = *(const f16x8*)(Pw + lr * 128 + c0);
        #pragma unroll
        for (int jd = 0; jd < 4; ++jd) {
          f16x8 vb = *(const f16x8*)(Vs + (jd * 16 + lr) * 128 + c0);
          O[i][jd] = __builtin_amdgcn_mfma_f32_16x16x32_f16(pa, vb, O[i][jd], 0, 0, 0);
        }
      }
      __builtin_amdgcn_s_setprio(0);
    }
    __syncthreads();
  }

  #pragma unroll
  for (int i = 0; i < 2; ++i)
    #pragma unroll
    for (int r = 0; r < 4; ++r) {
      int q = qblk * 128 + w * 32 + i * 16 + lg * 4 + r;
      float inv = 1.0f / lrow[i][r];
      #pragma unroll
      for (int jd = 0; jd < 4; ++jd) {
        int c = h * 64 + jd * 16 + lr;
        XO[((size_t)b * 512 + q) * 1024 + c] = (f16)(O[i][jd][r] * inv);
      }
    }
}

// ---------------------------------------------------------------------------
extern "C" void kernel_launch(void* const* d_in, const int* in_sizes, int n_in,
                              void* d_out, int out_size, void* d_ws, size_t ws_size,
                              hipStream_t stream)
{
  (void)in_sizes; (void)n_in; (void)out_size; (void)ws_size;
  const float* x            = (const float*)d_in[0];
  const unsigned char* mask = (const unsigned char*)d_in[1];
  const float* qkv_w   = (const float*)d_in[2];
  const float* qkv_la  = (const float*)d_in[3];
  const float* qkv_lb  = (const float*)d_in[4];
  const float* proj_w  = (const float*)d_in[5];
  const float* proj_b  = (const float*)d_in[6];
  const float* proj_la = (const float*)d_in[7];
  const float* proj_lb = (const float*)d_in[8];
  const float* fc1_w   = (const float*)d_in[9];
  const float* fc1_b   = (const float*)d_in[10];
  const float* fc1_la  = (const float*)d_in[11];
  const float* fc1_lb  = (const float*)d_in[12];
  const float* fc2_w   = (const float*)d_in[13];
  const float* fc2_b   = (const float*)d_in[14];
  const float* fc2_la  = (const float*)d_in[15];
  const float* fc2_lb  = (const float*)d_in[16];
  float* out = (float*)d_out;

  f16* p = (f16*)d_ws;
  f16* WqkvT = p; p += 3072 * 1024;
  f16* W1T   = p; p += 1024 * 1024;
  f16* W2T   = p; p += 1024 * 1024;
  f16* WpT   = p; p += 1024 * 1024;
  f16* Xh    = p; p += 4096 * 1024;
  f16* Qb    = p; p += 128 * 512 * 64;
  f16* Kb    = p; p += 128 * 512 * 64;
  f16* Vt    = p; p += 128 * 64 * 512;
  f16* XO    = p; p += 4096 * 1024;
  unsigned char* cmask = (unsigned char*)p;
  f16* Hb  = Qb;
  f16* XO2 = Xh;

  prep_all<<<3585, 256, 0, stream>>>(x, mask,
      qkv_w, qkv_la, qkv_lb, fc1_w, fc1_la, fc1_lb,
      fc2_w, fc2_la, fc2_lb, proj_w, proj_la, proj_lb,
      WqkvT, W1T, W2T, WpT, Xh, cmask);

  gemmk<0><<<dim3(32, 24), 256, 0, stream>>>(Xh, WqkvT, 4096, 3072, 1024,
      nullptr, nullptr, nullptr, nullptr, Qb, Kb, Vt);
  attn_kernel<<<dim3(4, 128), 256, 0, stream>>>(Qb, Kb, Vt, cmask, XO);
  gemm64<1><<<dim3(64, 16), 256, 0, stream>>>(XO, W1T, 4096, 1024, 1024,
      fc1_b, nullptr, Hb, nullptr);
  gemm64<2><<<dim3(64, 16), 256, 0, stream>>>(Hb, W2T, 4096, 1024, 1024,
      fc2_b, XO, XO2, nullptr);
  gemm64<3><<<dim3(64, 16), 256, 0, stream>>>(XO2, WpT, 4096, 1024, 1024,
      proj_b, nullptr, nullptr, out);
}